// Round 7
// baseline (825.626 us; speedup 1.0000x reference)
//
#include <hip/hip_runtime.h>
#include <stdint.h>

typedef uint16_t u16;
typedef short short8 __attribute__((ext_vector_type(8)));
typedef float f32x4 __attribute__((ext_vector_type(4)));

__device__ __forceinline__ u16 f2bf(float f){
  uint32_t u = __float_as_uint(f);
  u += 0x7fff + ((u >> 16) & 1);   // RNE
  return (u16)(u >> 16);
}

__device__ __forceinline__ void gload_lds16(const u16* g, const char* l){
  __builtin_amdgcn_global_load_lds((const __attribute__((address_space(1))) void*)g,
                                   (__attribute__((address_space(3))) void*)l,
                                   16, 0, 0);
}

// ---- prep: fp32 -> bf16 cast (vectorized, 8 elems/thread/iter) ----
__global__ void cast_bf16_kernel(const float* __restrict__ src, u16* __restrict__ dst, long n8){
  long i = (long)blockIdx.x * blockDim.x + threadIdx.x;
  long stride = (long)gridDim.x * blockDim.x;
  for (; i < n8; i += stride){
    float4 a = *(const float4*)(src + i*8);
    float4 b = *(const float4*)(src + i*8 + 4);
    u16 r[8] = {f2bf(a.x), f2bf(a.y), f2bf(a.z), f2bf(a.w),
                f2bf(b.x), f2bf(b.y), f2bf(b.z), f2bf(b.w)};
    *(uint4*)(dst + i*8) = *(const uint4*)r;
  }
}

// ---- prep: L = tril(pre) cast to bf16 ; layout (n,u,v) 8x512x512 ----
__global__ void mask_cast_L_kernel(const float* __restrict__ pre, u16* __restrict__ L){
  long i = (long)blockIdx.x * blockDim.x + threadIdx.x;  // chunk of 8 along v
  if (i >= 8L*512*64) return;
  int v0 = (int)(i & 63) * 8;
  int u  = (int)((i >> 6) & 511);
  float4 a = *(const float4*)(pre + i*8);
  float4 b = *(const float4*)(pre + i*8 + 4);
  float vals[8] = {a.x,a.y,a.z,a.w,b.x,b.y,b.z,b.w};
  u16 r[8];
  #pragma unroll
  for (int j=0;j<8;j++) r[j] = f2bf((v0 + j <= u) ? vals[j] : 0.0f);
  *(uint4*)(L + i*8) = *(const uint4*)r;
}

// ---- pipelined NT GEMM: C[M,N] = A(MxK,rm) * B(NxK,rm)^T ----
// 256x256 tile, BK=32, 8 waves (2Mx4N), wave 128x64, acc[8][4].
// 4 LDS buffers (32KB), stage 3 ahead, vmcnt(4), ONE barrier per K-tile.
// Fragment READ-AHEAD: frags(j+1) ds_reads issued BEFORE MM(j) so the LDS
// pipe services them while the matrix pipe runs (double frag sets, static
// indices). af2 (second A-half) single set, re-read after MM frees it.
// Swizzle g(r)=(r>>1)&3 on 16B chunks, both-sides (0 conflicts, r4-verified).
// tri: 1 = skip blocks entirely above diagonal (S-gemm); 2 = Keff=row0+256
// (O-gemm, A lower-triangular). EPI: 0 bf16; 1 +bias[row] bf16;
// 2 tril*scale bf16; 3 +bias[col] fp32.
template<int EPI, bool SWZ>
__global__ __launch_bounds__(512, 1)
void gemmp(const u16* __restrict__ A, const u16* __restrict__ B,
           void* __restrict__ Cv, int K, int lda, int ldb, int ldc,
           long asb, long asn, long bsb, long bsn, long csb, long csn,
           const float* __restrict__ bias, float scale, int tri)
{
  extern __shared__ __align__(16) char smem[];   // 4 * 32768 = 131072 B
  const int t = threadIdx.x;
  const int lane = t & 63;
  const int wave = t >> 6;          // 0..7
  const int wm = wave >> 2;         // 0..1
  const int wn = wave & 3;          // 0..3
  const long zb = blockIdx.z >> 3, zn = blockIdx.z & 7;
  A += zb*asb + zn*asn;
  B += zb*bsb + zn*bsn;

  int bx = blockIdx.x, by = blockIdx.y;
  if constexpr (SWZ){
    int nbx = gridDim.x;
    int bid = bx + by * nbx;
    int chunk = (nbx * gridDim.y) >> 3;   // blocks per XCD (grid % 8 == 0)
    int b2 = (bid & 7) * chunk + (bid >> 3);
    bx = b2 % nbx;  by = b2 / nbx;
  }
  const int row0 = by * 256, col0 = bx * 256;
  const int l15 = lane & 15, l4 = lane >> 4;

  // staging: thread t -> LDS slot t (16B), row = t>>2, chunk pos = t&3;
  // source chunk pre-swizzled: c_g = pos ^ g(row), g(r) = (r>>1)&3
  const int srow = t >> 2;                                // 0..127
  const int scol = (((t & 3) ^ ((srow >> 1) & 3)) * 8);   // elements
  const u16* gA = A + (long)(row0 + srow)*lda + scol;
  const u16* gB = B + (long)(col0 + srow)*ldb + scol;
  const long a128 = 128L*(long)lda, b128 = 128L*(long)ldb;
  const int ldst = t * 16;                                // byte slot

  // ds_read swizzled chunk: pos = l4 ^ g(row), g from l15
  const int csw = (l4 ^ ((l15 >> 1) & 3)) * 16;
  const int raw = (wm*128 + l15)*64 + csw;          // A read base (bytes)
  const int rbw = 16384 + (wn*64 + l15)*64 + csw;   // B read base

  f32x4 acc[8][4];
  #pragma unroll
  for (int m=0;m<8;m++)
    #pragma unroll
    for (int n=0;n<4;n++) acc[m][n] = (f32x4){0.f,0.f,0.f,0.f};

  int Keff = K;
  if (tri == 2) Keff = (row0 + 256 < K) ? (row0 + 256) : K;
  const int NT = Keff >> 5;                 // multiple of 4 (8/16/128)
  const bool skipall = (tri == 1) && (col0 >= row0 + 256);  // block-uniform

  if (!skipall){
    short8 bfS[2][4], af1S[2][4], af2[4];

#define STAGEM(PA, PB, BUF) { \
  gload_lds16((PA),        smem + (BUF)*32768 +         ldst); \
  gload_lds16((PA) + a128, smem + (BUF)*32768 +  8192 + ldst); \
  gload_lds16((PB),        smem + (BUF)*32768 + 16384 + ldst); \
  gload_lds16((PB) + b128, smem + (BUF)*32768 + 24576 + ldst); }

// BODY for tile j: CUR=j&3, NXT=(j+1)&3, P=j&1, Q=1-P. Reads frags(j+1),
// stages tile j+3, then 32 MFMA on frags(j), then af2(j+1), vmcnt, barrier.
#define BODY(CUR, NXT, P, Q, DOST, PA, PB, VMS) { \
  const char* bn_ = smem + (NXT)*32768; \
  _Pragma("unroll") \
  for (int n=0;n<4;n++) bfS[Q][n] = *(const short8*)(bn_ + rbw + n*1024); \
  _Pragma("unroll") \
  for (int m=0;m<4;m++) af1S[Q][m] = *(const short8*)(bn_ + raw + m*1024); \
  if (DOST) STAGEM(PA, PB, ((CUR)+3)&3) \
  __builtin_amdgcn_sched_barrier(0); \
  __builtin_amdgcn_s_setprio(1); \
  _Pragma("unroll") \
  for (int m=0;m<4;m++) \
    _Pragma("unroll") \
    for (int n=0;n<4;n++) \
      acc[m][n] = __builtin_amdgcn_mfma_f32_16x16x32_bf16(af1S[P][m], bfS[P][n], acc[m][n],0,0,0); \
  _Pragma("unroll") \
  for (int m=0;m<4;m++) \
    _Pragma("unroll") \
    for (int n=0;n<4;n++) \
      acc[m+4][n] = __builtin_amdgcn_mfma_f32_16x16x32_bf16(af2[m], bfS[P][n], acc[m+4][n],0,0,0); \
  __builtin_amdgcn_s_setprio(0); \
  __builtin_amdgcn_sched_barrier(0); \
  _Pragma("unroll") \
  for (int m=0;m<4;m++) af2[m] = *(const short8*)(bn_ + raw + (m+4)*1024); \
  asm volatile("s_waitcnt vmcnt(" VMS ")" ::: "memory"); \
  __builtin_amdgcn_s_barrier(); \
  asm volatile("" ::: "memory"); }

    // prologue: stage tiles 0,1,2; wait 0,1 landed; load frags(0)
    STAGEM(gA,      gB,      0)
    STAGEM(gA + 32, gB + 32, 1)
    STAGEM(gA + 64, gB + 64, 2)
    asm volatile("s_waitcnt vmcnt(4)" ::: "memory");
    __builtin_amdgcn_s_barrier();
    asm volatile("" ::: "memory");
    {
      const char* b0_ = smem;
      #pragma unroll
      for (int n=0;n<4;n++) bfS[0][n]  = *(const short8*)(b0_ + rbw + n*1024);
      #pragma unroll
      for (int m=0;m<4;m++) af1S[0][m] = *(const short8*)(b0_ + raw + m*1024);
      #pragma unroll
      for (int m=0;m<4;m++) af2[m]     = *(const short8*)(b0_ + raw + (m+4)*1024);
    }

    // main: 4 tiles per iter; body(j) stages tile j+3
    #pragma unroll 1
    for (int tb = 0; tb < NT - 4; tb += 4){
      const u16* pa = gA + (long)(tb + 3)*32;
      const u16* pb = gB + (long)(tb + 3)*32;
      BODY(0, 1, 0, 1, true, pa,      pb,      "4")
      BODY(1, 2, 1, 0, true, pa + 32, pb + 32, "4")
      BODY(2, 3, 0, 1, true, pa + 64, pb + 64, "4")
      BODY(3, 0, 1, 0, true, pa + 96, pb + 96, "4")
    }
    // tail: tiles NT-4..NT-1; one last stage (tile NT-1); exact drains
    {
      const u16* pa = gA + (long)(NT - 1)*32;
      const u16* pb = gB + (long)(NT - 1)*32;
      BODY(0, 1, 0, 1, true,  pa, pb, "4")
      BODY(1, 2, 1, 0, false, pa, pb, "0")
      BODY(2, 3, 0, 1, false, pa, pb, "0")
      BODY(3, 0, 1, 0, false, pa, pb, "0")
    }
#undef STAGEM
#undef BODY
  }

  // epilogue: C/D map col=lane&15, row=(lane>>4)*4+g  (HW-verified)
  if constexpr (EPI == 3){
    float* C = (float*)Cv;
    #pragma unroll
    for (int m=0;m<8;m++){
      int r0 = row0 + wm*128 + m*16 + l4*4;
      #pragma unroll
      for (int n=0;n<4;n++){
        int c = col0 + wn*64 + n*16 + l15;
        float bc = bias[c];
        #pragma unroll
        for (int g=0; g<4; g++)
          C[(long)(r0+g)*ldc + c] = acc[m][n][g] + bc;
      }
    }
  } else {
    u16* C = (u16*)Cv + zb*csb + zn*csn;
    #pragma unroll
    for (int m=0;m<8;m++){
      int r0 = row0 + wm*128 + m*16 + l4*4;
      #pragma unroll
      for (int n=0;n<4;n++){
        int c = col0 + wn*64 + n*16 + l15;
        #pragma unroll
        for (int g=0;g<4;g++){
          float v = acc[m][n][g];
          int r = r0 + g;
          if constexpr (EPI==1) v += bias[r];
          if constexpr (EPI==2) v = (c <= r) ? v*scale : 0.0f;
          C[(long)r*ldc + c] = f2bf(v);
        }
      }
    }
  }
}

// Workspace layout (bytes):
//   xb   @ 0          : 8192x4096 bf16
//   W1b  @ 67108864   : 4096x4096 bf16
//   W2b  @ 100663296  : 4096x4096 bf16
//   Lb   @ 134217728  : 8x512x512 bf16
//   Mb   @ 138412032  : 8x512x512 bf16
//   PtG  @ 142606336  : 4096x8192 bf16   PtG[c][r] = P_full[r][c]
//   MPt  @ 209715200  : 128x512x512 bf16 MPt[z][j][u] = MP[b,n,u,j]
//   Sb   @ 276824064  : 128x512x512 bf16
//   Ob   = MPt (reuse; MPt dead after S-gemm)

#define LDSB 131072

extern "C" void kernel_launch(void* const* d_in, const int* in_sizes, int n_in,
                              void* d_out, int out_size, void* d_ws, size_t ws_size,
                              hipStream_t stream)
{
  (void)in_sizes; (void)n_in; (void)out_size; (void)ws_size;
  const float* x   = (const float*)d_in[0];
  const float* W1  = (const float*)d_in[1];
  const float* b1  = (const float*)d_in[2];
  const float* pre = (const float*)d_in[3];
  const float* W2  = (const float*)d_in[4];
  const float* b2  = (const float*)d_in[5];
  float* out = (float*)d_out;
  char* ws = (char*)d_ws;

  u16* xb  = (u16*)(ws + 0L);
  u16* W1b = (u16*)(ws + 67108864L);
  u16* W2b = (u16*)(ws + 100663296L);
  u16* Lb  = (u16*)(ws + 134217728L);
  u16* Mb  = (u16*)(ws + 138412032L);
  u16* Pt  = (u16*)(ws + 142606336L);
  u16* MPt = (u16*)(ws + 209715200L);
  u16* Sb  = (u16*)(ws + 276824064L);
  u16* Ob  = MPt;  // reuse: MPt consumed by S-gemm before O-gemm writes

  hipFuncSetAttribute((const void*)gemmp<0,false>, hipFuncAttributeMaxDynamicSharedMemorySize, LDSB);
  hipFuncSetAttribute((const void*)gemmp<1,true >, hipFuncAttributeMaxDynamicSharedMemorySize, LDSB);
  hipFuncSetAttribute((const void*)gemmp<2,false>, hipFuncAttributeMaxDynamicSharedMemorySize, LDSB);
  hipFuncSetAttribute((const void*)gemmp<3,true >, hipFuncAttributeMaxDynamicSharedMemorySize, LDSB);

  // preps
  cast_bf16_kernel<<<4096,256,0,stream>>>(x,  xb,  4194304L);
  cast_bf16_kernel<<<4096,256,0,stream>>>(W1, W1b, 2097152L);
  cast_bf16_kernel<<<4096,256,0,stream>>>(W2, W2b, 2097152L);
  mask_cast_L_kernel<<<1024,256,0,stream>>>(pre, Lb);

  // M[n] = L[n] ·NT· L[n]          (8 batches, 512^3)
  gemmp<0,false><<<dim3(2,2,8),512,LDSB,stream>>>(Lb, Lb, Mb, 512, 512,512,512,
      0, 262144, 0, 262144, 0, 262144, nullptr, 0.f, 0);

  // PtG = W1b ·NT· xb + b1[row]    (4096 x 8192, K=4096)
  gemmp<1,true><<<dim3(32,16,1),512,LDSB,stream>>>(W1b, xb, Pt, 4096, 4096,4096,8192,
      0,0, 0,0, 0,0, b1, 0.f, 0);

  // MPt[z] = Pt(b,n) ·NT· M[n]     (128 batches, 512^3)
  gemmp<0,false><<<dim3(2,2,128),512,LDSB,stream>>>(Pt, Mb, MPt, 512, 8192,512,512,
      512, 512L*8192, 0, 262144, 8L*262144, 262144, nullptr, 0.f, 0);

  // S[z] = Pt(b,n) ·NT· MPt[z], *1/sqrt(512), tril mask; skip upper blocks
  gemmp<2,false><<<dim3(2,2,128),512,LDSB,stream>>>(Pt, MPt, Sb, 512, 8192,512,512,
      512, 512L*8192, 8L*262144, 262144, 8L*262144, 262144, nullptr, 0.04419417382f, 1);

  // O(b,n) = S[z] ·NT· Pt(b,n) -> Ob; S lower-tri => Keff = row0+256
  gemmp<0,false><<<dim3(2,2,128),512,LDSB,stream>>>(Sb, Pt, Ob, 512, 512,8192,4096,
      8L*262144, 262144, 512, 512L*8192, 512L*4096, 512, nullptr, 0.f, 2);

  // Y = Ob ·NT· W2b + b2[col]      (8192 x 4096, K=4096, fp32 out)
  gemmp<3,true><<<dim3(16,32,1),512,LDSB,stream>>>(Ob, W2b, out, 4096, 4096,4096,4096,
      0,0, 0,0, 0,0, b2, 0.f, 0);
}